// Round 1
// baseline (241.186 us; speedup 1.0000x reference)
//
#include <hip/hip_runtime.h>
#include <hip/hip_bf16.h>

// Sizes from the reference
#define B_  16
#define N_  256
#define L_  64
#define H_  32
#define HE_ 128
#define EO_ 64

typedef __attribute__((ext_vector_type(8))) short bf16x8;
typedef __attribute__((ext_vector_type(4))) float f32x4;

__device__ __forceinline__ unsigned cvt_pk_bf16(float a, float b) {
  unsigned r;
  asm("v_cvt_pk_bf16_f32 %0, %1, %2" : "=v"(r) : "v"(a), "v"(b));
  return r;
}

// ---------------------------------------------------------------------------
// Setup (once): Wp = 0.6*We1[:H]@We2, Wq = 0.6*We1[H:]@We2,
// bp = 0.6*be1@We2 + be2, and Bfrag = 0.4*We2 in bf16 MFMA B-fragment layout.
// grid (8,3), block 256
// ---------------------------------------------------------------------------
__global__ void k_setup(const float* __restrict__ We1, const float* __restrict__ be1,
                        const float* __restrict__ We2, const float* __restrict__ be2,
                        float* __restrict__ Wp, float* __restrict__ Wq,
                        float* __restrict__ bp, uint4* __restrict__ Bfrag) {
  const int t   = blockIdx.y;
  const int gid = blockIdx.x * 256 + threadIdx.x;   // 0..2047
  const float* We1t = We1 + t * 64 * 128;
  const float* We2t = We2 + t * 128 * 64;

  { // Wp / Wq: 32x64 outputs each
    int f = gid >> 6, o = gid & 63;
    float ap = 0.f, aq = 0.f;
    for (int k = 0; k < 128; ++k) {
      float w2 = We2t[k * 64 + o];
      ap += We1t[f * 128 + k] * w2;
      aq += We1t[(32 + f) * 128 + k] * w2;
    }
    Wp[(t * 32 + f) * 64 + o] = 0.6f * ap;
    Wq[(t * 32 + f) * 64 + o] = 0.6f * aq;
  }
  if (gid < 64) {
    float ab = be2[t * 64 + gid];
    for (int k = 0; k < 128; ++k) ab += 0.6f * be1[t * 128 + k] * We2t[k * 64 + gid];
    bp[t * 64 + gid] = ab;
  }
  // Bfrag: 1024 uint4 per t; frag map: k = kk*32 + (lane>>4)*8 + e, o = nt*16 + (lane&15)
  if (gid < 1024) {
    int u = gid;
    int kk = u >> 8, nt = (u >> 6) & 3, ln = u & 63;
    int k0 = kk * 32 + (ln >> 4) * 8, o = nt * 16 + (ln & 15);
    unsigned w[4];
#pragma unroll
    for (int p = 0; p < 4; ++p) {
      float v0 = 0.4f * We2t[(k0 + 2 * p) * 64 + o];
      float v1 = 0.4f * We2t[(k0 + 2 * p + 1) * 64 + o];
      w[p] = cvt_pk_bf16(v0, v1);
    }
    Bfrag[t * 1024 + u] = make_uint4(w[0], w[1], w[2], w[3]);
  }
}

// ---------------------------------------------------------------------------
// Init: h[b,n,:] = (x[b,:] @ W_lin[:, n*64:(n+1)*64] + b_lin) @ W_in + b_in
// grid 1024, block 256 (one wave per (b,n) row)
// ---------------------------------------------------------------------------
__global__ __launch_bounds__(256) void k_init(const float* __restrict__ x,
                                              const float* __restrict__ W_lin,
                                              const float* __restrict__ b_lin,
                                              const float* __restrict__ W_in,
                                              const float* __restrict__ b_in,
                                              float* __restrict__ h) {
  __shared__ float sm[4][64];
  const int w = threadIdx.x >> 6, lane = threadIdx.x & 63;
  const int row = __builtin_amdgcn_readfirstlane(blockIdx.x * 4 + w);
  const int b = row >> 8, n = row & 255;
  float acc = b_lin[n * 64 + lane];
  const float* xb = x + b * 64;
  for (int l = 0; l < 64; ++l)
    acc += xb[l] * W_lin[l * (N_ * L_) + n * 64 + lane];
  sm[w][lane] = acc;
  __syncthreads();
  if (lane < 32) {
    float hacc = b_in[lane];
#pragma unroll 8
    for (int f = 0; f < 64; ++f) hacc += sm[w][f] * W_in[f * 32 + lane];
    h[row * 32 + lane] = hacc;
  }
}

// ---------------------------------------------------------------------------
// Projection per round: R' = h@We1[:H]+be1, S = h@We1[H:], P = h@Wp+bp, Q = h@Wq
// grid 1024, block 256 (one wave per row)
// ---------------------------------------------------------------------------
__global__ __launch_bounds__(256) void k_proj(const float* __restrict__ h,
                                              const float* __restrict__ We1,
                                              const float* __restrict__ be1,
                                              const float* __restrict__ Wp,
                                              const float* __restrict__ Wq,
                                              const float* __restrict__ bp,
                                              float* __restrict__ Rp, float* __restrict__ S,
                                              float* __restrict__ P, float* __restrict__ Q,
                                              int t) {
  const int lane = threadIdx.x & 63;
  const int row = __builtin_amdgcn_readfirstlane(blockIdx.x * 4 + (threadIdx.x >> 6));
  const float* hr = h + row * 32;
  const float* We1t = We1 + t * 64 * 128;
  float r0 = be1[t * 128 + lane], r1 = be1[t * 128 + 64 + lane];
  float s0 = 0.f, s1 = 0.f;
  float p = bp[t * 64 + lane], q = 0.f;
  for (int f = 0; f < 32; ++f) {
    float hf = hr[f];
    r0 += hf * We1t[f * 128 + lane];
    r1 += hf * We1t[f * 128 + 64 + lane];
    s0 += hf * We1t[(32 + f) * 128 + lane];
    s1 += hf * We1t[(32 + f) * 128 + 64 + lane];
    p  += hf * Wp[(t * 32 + f) * 64 + lane];
    q  += hf * Wq[(t * 32 + f) * 64 + lane];
  }
  Rp[row * 128 + lane] = r0;  Rp[row * 128 + 64 + lane] = r1;
  S [row * 128 + lane] = s0;  S [row * 128 + 64 + lane] = s1;
  P [row * 64 + lane]  = p;   Q [row * 64 + lane]       = q;
}

// ---------------------------------------------------------------------------
// Fused edge-MLP + aggregate + node-MLP per round.
// grid (16 i-tiles, 16 b), block 512 (8 waves; wave w handles j in [32w,32w+32))
// Each wave: m_tile[16 i x 64 o] output-stationary; per j:
//   A = bf16(|R'[i,k] + S[j,k]|), C-init = P[i,o]+Q[j,o],
//   acc = A @ (0.4*We2) + C   (16 MFMA 16x16x32)
//   m += max(acc, 0.2*acc)
// Then LDS tree-reduce 8 partials, node MLP, write h' (or tanh -> out).
// ---------------------------------------------------------------------------
template <bool LAST>
__global__ __launch_bounds__(512, 2) void k_edge(
    const float* __restrict__ Rp, const float* __restrict__ S,
    const float* __restrict__ P, const float* __restrict__ Q,
    const uint4* __restrict__ Bfrag,
    const float* __restrict__ Wn0, const float* __restrict__ bn0,
    const float* __restrict__ Wn1, const float* __restrict__ bn1,
    float* __restrict__ h_io, float* __restrict__ out, int t) {
  const int b  = blockIdx.y;
  const int i0 = blockIdx.x * 16;
  const int tid = threadIdx.x;
  const int w = tid >> 6, lane = tid & 63;
  const int col = lane & 15, kg = lane >> 4;

  __shared__ float h_tile[16 * 33];
  __shared__ float mred[8 * 1040];   // 8 partial tiles, stride 65 per row
  __shared__ float mfin[16 * 65];
  __shared__ float n_lds[16 * 33];

  { // stage h rows for the node phase
    int il = tid >> 5, o = tid & 31;
    h_tile[il * 33 + o] = h_io[((b << 8) + i0 + il) * 32 + o];
  }

  union BU { uint4 q; bf16x8 v; };
  BU bfr[4][4];
#pragma unroll
  for (int kk = 0; kk < 4; ++kk)
#pragma unroll
    for (int nt = 0; nt < 4; ++nt)
      bfr[kk][nt].q = Bfrag[((t * 4 + kk) * 4 + nt) * 64 + lane];

  // receiver contribution (j-invariant): R'[i0+col, kk*32+kg*8 + 0..7]
  float4 rA[4][2];
  const float* rB = Rp + (size_t)((b << 8) + i0 + col) * 128 + kg * 8;
#pragma unroll
  for (int kk = 0; kk < 4; ++kk) {
    rA[kk][0] = *(const float4*)(rB + kk * 32);
    rA[kk][1] = *(const float4*)(rB + kk * 32 + 4);
  }

  // P in C-layout: row i = i0 + kg*4 + r, col o = nt*16 + col
  float pb[4][4];
#pragma unroll
  for (int nt = 0; nt < 4; ++nt)
#pragma unroll
    for (int r = 0; r < 4; ++r)
      pb[nt][r] = P[(size_t)((b << 8) + i0 + kg * 4 + r) * 64 + nt * 16 + col];

  float m[4][4] = {};
  const float* sB = S + (size_t)(b << 8) * 128 + kg * 8;
  const float* qB = Q + (size_t)(b << 8) * 64 + col;

  const int j0 = w * 32;
  for (int j = j0; j < j0 + 32; ++j) {
    const float* sj = sB + (size_t)j * 128;
    float qv[4];
#pragma unroll
    for (int nt = 0; nt < 4; ++nt) qv[nt] = qB[(size_t)j * 64 + nt * 16];

    BU af[4];
#pragma unroll
    for (int kk = 0; kk < 4; ++kk) {
      float4 s0 = *(const float4*)(sj + kk * 32);
      float4 s1 = *(const float4*)(sj + kk * 32 + 4);
      float4 r0 = rA[kk][0], r1 = rA[kk][1];
      unsigned u0 = cvt_pk_bf16(fabsf(r0.x + s0.x), fabsf(r0.y + s0.y));
      unsigned u1 = cvt_pk_bf16(fabsf(r0.z + s0.z), fabsf(r0.w + s0.w));
      unsigned u2 = cvt_pk_bf16(fabsf(r1.x + s1.x), fabsf(r1.y + s1.y));
      unsigned u3 = cvt_pk_bf16(fabsf(r1.z + s1.z), fabsf(r1.w + s1.w));
      af[kk].q = make_uint4(u0, u1, u2, u3);
    }

    f32x4 acc[4];
#pragma unroll
    for (int nt = 0; nt < 4; ++nt) {
      float q = qv[nt];
      f32x4 c;
      c[0] = pb[nt][0] + q; c[1] = pb[nt][1] + q;
      c[2] = pb[nt][2] + q; c[3] = pb[nt][3] + q;
      acc[nt] = c;
    }
#pragma unroll
    for (int kk = 0; kk < 4; ++kk)
#pragma unroll
      for (int nt = 0; nt < 4; ++nt)
        acc[nt] = __builtin_amdgcn_mfma_f32_16x16x32_bf16(af[kk].v, bfr[kk][nt].v, acc[nt], 0, 0, 0);

#pragma unroll
    for (int nt = 0; nt < 4; ++nt)
#pragma unroll
      for (int r = 0; r < 4; ++r) {
        float e = acc[nt][r];
        m[nt][r] += fmaxf(e, 0.2f * e);   // lrelu on e2, sum over j
      }
  }

  // write partial m tiles
#pragma unroll
  for (int nt = 0; nt < 4; ++nt)
#pragma unroll
    for (int r = 0; r < 4; ++r)
      mred[w * 1040 + (kg * 4 + r) * 65 + nt * 16 + col] = m[nt][r];
  __syncthreads();

  // reduce 8 partials -> mfin
  for (int e = tid; e < 1024; e += 512) {
    int il = e >> 6, o = e & 63;
    float s = 0.f;
#pragma unroll
    for (int w2 = 0; w2 < 8; ++w2) s += mred[w2 * 1040 + il * 65 + o];
    mfin[il * 65 + o] = s;
  }
  __syncthreads();

  // node MLP layer 0: n = lrelu([h, m] @ Wn0 + bn0)
  {
    int il = tid >> 5, o = tid & 31;
    float a0 = bn0[t * 32 + o];
    const float* w0 = Wn0 + (size_t)t * 96 * 32 + o;
#pragma unroll 8
    for (int f = 0; f < 32; ++f) a0 += h_tile[il * 33 + f] * w0[f * 32];
#pragma unroll 8
    for (int f = 0; f < 64; ++f) a0 += mfin[il * 65 + f] * w0[(32 + f) * 32];
    a0 = fmaxf(a0, 0.2f * a0);
    n_lds[il * 33 + o] = a0;
  }
  __syncthreads();

  // node MLP layer 1: h' = lrelu(n @ Wn1 + bn1); last round: tanh -> out
  {
    int il = tid >> 5, o = tid & 31;
    float a1 = bn1[t * 32 + o];
    const float* w1 = Wn1 + (size_t)t * 32 * 32 + o;
#pragma unroll 8
    for (int f = 0; f < 32; ++f) a1 += n_lds[il * 33 + f] * w1[f * 32];
    a1 = fmaxf(a1, 0.2f * a1);
    int gi = ((b << 8) + i0 + il) * 32 + o;
    if (LAST) out[gi] = tanhf(a1);
    else      h_io[gi] = a1;
  }
}

// ---------------------------------------------------------------------------
extern "C" void kernel_launch(void* const* d_in, const int* in_sizes, int n_in,
                              void* d_out, int out_size, void* d_ws, size_t ws_size,
                              hipStream_t stream) {
  const float* x     = (const float*)d_in[0];
  const float* W_lin = (const float*)d_in[1];
  const float* b_lin = (const float*)d_in[2];
  const float* W_in  = (const float*)d_in[3];
  const float* b_in  = (const float*)d_in[4];
  const float* We1   = (const float*)d_in[5];
  const float* be1   = (const float*)d_in[6];
  const float* We2   = (const float*)d_in[7];
  const float* be2   = (const float*)d_in[8];
  const float* Wn0   = (const float*)d_in[9];
  const float* bn0   = (const float*)d_in[10];
  const float* Wn1   = (const float*)d_in[11];
  const float* bn1   = (const float*)d_in[12];
  float* out = (float*)d_out;

  float* ws = (float*)d_ws;
  float* h  = ws;                  // 131072 f32
  float* Rp = ws + 131072;         // 524288
  float* Sb = ws + 655360;         // 524288
  float* Pb = ws + 1179648;        // 262144
  float* Qb = ws + 1441792;        // 262144
  float* Wp = ws + 1703936;        // 6144
  float* Wq = ws + 1710080;        // 6144
  float* bp = ws + 1716224;        // 192
  uint4* Bf = (uint4*)(ws + 1716416); // 3072 uint4 (48 KB)

  k_setup<<<dim3(8, 3), 256, 0, stream>>>(We1, be1, We2, be2, Wp, Wq, bp, Bf);
  k_init<<<1024, 256, 0, stream>>>(x, W_lin, b_lin, W_in, b_in, h);
  for (int t = 0; t < 3; ++t) {
    k_proj<<<1024, 256, 0, stream>>>(h, We1, be1, Wp, Wq, bp, Rp, Sb, Pb, Qb, t);
    if (t < 2)
      k_edge<false><<<dim3(16, 16), 512, 0, stream>>>(Rp, Sb, Pb, Qb, Bf,
                                                      Wn0, bn0, Wn1, bn1, h, nullptr, t);
    else
      k_edge<true><<<dim3(16, 16), 512, 0, stream>>>(Rp, Sb, Pb, Qb, Bf,
                                                     Wn0, bn0, Wn1, bn1, h, out, t);
  }
}